// Round 1
// baseline (791.911 us; speedup 1.0000x reference)
//
#include <hip/hip_runtime.h>

typedef unsigned short ushort_t;
typedef __attribute__((ext_vector_type(8))) unsigned short ushort8;
typedef __attribute__((ext_vector_type(4))) unsigned short ushortv4;
typedef __attribute__((ext_vector_type(8))) __bf16 bf16x8;
typedef __attribute__((ext_vector_type(4))) float f32x4;

#define BATCH   2
#define SEQLEN  2048
#define BL      4096
#define DMODEL  1024
#define DINNER  2048
#define DSTATE  128
#define NHEADS  16
#define DXBC    2304
#define DPROJ   4368
#define NPAD    4480
#define EPSF    1e-5f

__device__ __forceinline__ float bf2f(ushort_t h) {
    unsigned int u = ((unsigned int)h) << 16;
    float f; __builtin_memcpy(&f, &u, 4); return f;
}
__device__ __forceinline__ ushort_t f2bf(float f) {
    unsigned int u; __builtin_memcpy(&u, &f, 4);
    unsigned int r = u + 0x7fffu + ((u >> 16) & 1u);
    return (ushort_t)(r >> 16);
}
__device__ __forceinline__ float siluf(float x) { return x / (1.f + expf(-x)); }
__device__ __forceinline__ float softplusf(float x) { return (x > 20.f) ? x : log1pf(expf(x)); }

// ---------------- LayerNorm + cast to bf16 ----------------
__global__ __launch_bounds__(256) void ln_kernel(const float* __restrict__ x,
        const float* __restrict__ w, const float* __restrict__ b, ushort_t* __restrict__ xn) {
    int r = blockIdx.x, t = threadIdx.x;
    const float* xr = x + (size_t)r * DMODEL;
    float4 v = *(const float4*)&xr[t * 4];
    float s  = v.x + v.y + v.z + v.w;
    float sq = v.x*v.x + v.y*v.y + v.z*v.z + v.w*v.w;
    __shared__ float red[8];
    #pragma unroll
    for (int m = 32; m >= 1; m >>= 1) { s += __shfl_xor(s, m, 64); sq += __shfl_xor(sq, m, 64); }
    int wv = t >> 6;
    if ((t & 63) == 0) { red[wv] = s; red[4 + wv] = sq; }
    __syncthreads();
    s  = red[0] + red[1] + red[2] + red[3];
    sq = red[4] + red[5] + red[6] + red[7];
    float mu  = s * (1.f / DMODEL);
    float var = sq * (1.f / DMODEL) - mu * mu;
    float inv = rsqrtf(var + EPSF);
    float4 wv4 = *(const float4*)&w[t * 4];
    float4 bv4 = *(const float4*)&b[t * 4];
    ushortv4 o;
    o[0] = f2bf((v.x - mu) * inv * wv4.x + bv4.x);
    o[1] = f2bf((v.y - mu) * inv * wv4.y + bv4.y);
    o[2] = f2bf((v.z - mu) * inv * wv4.z + bv4.z);
    o[3] = f2bf((v.w - mu) * inv * wv4.w + bv4.w);
    *(ushortv4*)&xn[(size_t)r * DMODEL + t * 4] = o;
}

// ---------------- transpose + cast f32[K][N] -> bf16[Npad][K] ----------------
__global__ __launch_bounds__(256) void transpose_cast(const float* __restrict__ W,
        ushort_t* __restrict__ WT, int K, int N) {
    __shared__ float tile[32][33];
    int n0 = blockIdx.x * 32, k0 = blockIdx.y * 32;
    int tx = threadIdx.x & 31, ty = threadIdx.x >> 5;
    #pragma unroll
    for (int i = 0; i < 32; i += 8) {
        int n = n0 + tx;
        tile[ty + i][tx] = (n < N) ? W[(size_t)(k0 + ty + i) * N + n] : 0.f;
    }
    __syncthreads();
    #pragma unroll
    for (int i = 0; i < 32; i += 8) {
        WT[(size_t)(n0 + ty + i) * K + k0 + tx] = f2bf(tile[tx][ty + i]);
    }
}

// ---------------- GEMM: C[M][ldc] = A[M][K](bf16) @ BT[N][K](bf16)^T (+resid) ----------------
__global__ __launch_bounds__(256) void gemm_bt(const ushort_t* __restrict__ A,
        const ushort_t* __restrict__ BT, float* __restrict__ C,
        const float* __restrict__ resid, int K, int ldc) {
    const int tid = threadIdx.x;
    const int m0 = blockIdx.y * 128, n0 = blockIdx.x * 128;
    __shared__ ushort_t As[128 * 32];
    __shared__ ushort_t Bs[128 * 32];
    const int row = tid >> 1;
    const int kh  = (tid & 1) * 16;
    const ushort_t* Ag = A  + (size_t)(m0 + row) * K + kh;
    const ushort_t* Bg = BT + (size_t)(n0 + row) * K + kh;
    ushort8 ra0 = *(const ushort8*)(Ag),     ra1 = *(const ushort8*)(Ag + 8);
    ushort8 rb0 = *(const ushort8*)(Bg),     rb1 = *(const ushort8*)(Bg + 8);
    const int lane = tid & 63, wave = tid >> 6;
    const int wm = (wave >> 1) * 64, wn = (wave & 1) * 64;
    const int fr = lane & 15, ko = (lane >> 4) * 8;
    f32x4 acc[4][4];
    #pragma unroll
    for (int i = 0; i < 4; i++)
        #pragma unroll
        for (int j = 0; j < 4; j++) acc[i][j] = (f32x4){0.f, 0.f, 0.f, 0.f};
    for (int k0 = 0; k0 < K; k0 += 32) {
        __syncthreads();
        *(ushort8*)&As[row * 32 + kh]     = ra0;
        *(ushort8*)&As[row * 32 + kh + 8] = ra1;
        *(ushort8*)&Bs[row * 32 + kh]     = rb0;
        *(ushort8*)&Bs[row * 32 + kh + 8] = rb1;
        __syncthreads();
        if (k0 + 32 < K) {
            ra0 = *(const ushort8*)(Ag + k0 + 32); ra1 = *(const ushort8*)(Ag + k0 + 40);
            rb0 = *(const ushort8*)(Bg + k0 + 32); rb1 = *(const ushort8*)(Bg + k0 + 40);
        }
        bf16x8 af[4], bfr[4];
        #pragma unroll
        for (int i = 0; i < 4; i++) af[i]  = *(const bf16x8*)&As[(wm + i * 16 + fr) * 32 + ko];
        #pragma unroll
        for (int j = 0; j < 4; j++) bfr[j] = *(const bf16x8*)&Bs[(wn + j * 16 + fr) * 32 + ko];
        #pragma unroll
        for (int i = 0; i < 4; i++)
            #pragma unroll
            for (int j = 0; j < 4; j++)
                acc[i][j] = __builtin_amdgcn_mfma_f32_16x16x32_bf16(af[i], bfr[j], acc[i][j], 0, 0, 0);
    }
    const int r0 = (lane >> 4) * 4;
    #pragma unroll
    for (int i = 0; i < 4; i++)
        #pragma unroll
        for (int j = 0; j < 4; j++)
            #pragma unroll
            for (int r = 0; r < 4; r++) {
                int m = m0 + wm + i * 16 + r0 + r;
                int n = n0 + wn + j * 16 + fr;
                float v = acc[i][j][r];
                if (resid) v += resid[(size_t)m * ldc + n];
                C[(size_t)m * ldc + n] = v;
            }
}

// ---------------- conv4 + SiLU + split + dt/dA ----------------
__global__ __launch_bounds__(256) void conv_kernel(const float* __restrict__ zxb,
        const float* __restrict__ conv_w, const float* __restrict__ conv_b,
        const float* __restrict__ dt_bias, const float* __restrict__ A_log,
        ushort_t* __restrict__ xcv, ushort_t* __restrict__ Bcg, ushort_t* __restrict__ Ccg,
        float* __restrict__ dtv, float* __restrict__ dAv) {
    int bid = blockIdx.x;
    int l = bid & (SEQLEN - 1);
    int tid = threadIdx.x;
    const float* rowp = zxb + (size_t)bid * NPAD;
    #pragma unroll 1
    for (int i = 0; i < 9; i++) {
        int c = tid + i * 256;
        float acc = conv_b[c];
        #pragma unroll
        for (int k = 0; k < 4; k++) {
            int ll = l - 3 + k;
            if (ll >= 0) acc += rowp[(ptrdiff_t)(k - 3) * NPAD + DINNER + c] * conv_w[c * 4 + k];
        }
        float v = siluf(acc);
        if (c < DINNER)                xcv[(size_t)bid * DINNER + c] = f2bf(v);
        else if (c < DINNER + DSTATE)  Bcg[(size_t)bid * DSTATE + (c - DINNER)] = f2bf(v);
        else                           Ccg[(size_t)bid * DSTATE + (c - DINNER - DSTATE)] = f2bf(v);
    }
    if (tid < NHEADS) {
        float raw = rowp[DINNER + DXBC + tid] + dt_bias[tid];
        float dt = softplusf(raw);
        float A = -expf(A_log[tid]);
        dtv[(size_t)bid * NHEADS + tid] = dt;
        dAv[(size_t)bid * NHEADS + tid] = expf(dt * A);
    }
}

// ---------------- SSM scan: grid (p-slice 8, h 16, b 2) ----------------
__global__ __launch_bounds__(256) void scan_kernel(const ushort_t* __restrict__ xcv,
        const ushort_t* __restrict__ Bcg, const ushort_t* __restrict__ Ccg,
        const float* __restrict__ dtv, const float* __restrict__ dAv,
        const float* __restrict__ Dvec, ushort_t* __restrict__ yv) {
    const int ps = blockIdx.x, h = blockIdx.y, b = blockIdx.z;
    const int tid = threadIdx.x;
    const int pl = tid >> 4, nc = tid & 15;
    __shared__ ushort_t Bsh[32][128];
    __shared__ ushort_t Csh[32][128];
    __shared__ float xs[32][16];
    __shared__ float ysh[32][16];
    __shared__ float dts[32];
    __shared__ float dAs[32];
    float s[8];
    #pragma unroll
    for (int j = 0; j < 8; j++) s[j] = 0.f;
    const float Dh = Dvec[h];
    const size_t base = (size_t)b * SEQLEN;
    const int pcol = h * 128 + ps * 16;
    for (int t0 = 0; t0 < SEQLEN; t0 += 32) {
        #pragma unroll
        for (int i = 0; i < 2; i++) {
            int idx = tid + i * 256;             // 0..511 : ushort8 units
            int r = idx >> 4, c8 = (idx & 15) * 8;
            *(ushort8*)&Bsh[r][c8] = *(const ushort8*)&Bcg[(base + t0 + r) * DSTATE + c8];
            *(ushort8*)&Csh[r][c8] = *(const ushort8*)&Ccg[(base + t0 + r) * DSTATE + c8];
            xs[r][idx & 15] = bf2f(xcv[(base + t0 + r) * DINNER + pcol + (idx & 15)]);
        }
        if (tid < 32) {
            dts[tid] = dtv[(base + t0 + tid) * NHEADS + h];
            dAs[tid] = dAv[(base + t0 + tid) * NHEADS + h];
        }
        __syncthreads();
        #pragma unroll 1
        for (int tt = 0; tt < 32; tt++) {
            float dA = dAs[tt], dt = dts[tt], xp = xs[tt][pl];
            float a = dt * xp;
            ushort8 Bv = *(const ushort8*)&Bsh[tt][nc * 8];
            ushort8 Cv = *(const ushort8*)&Csh[tt][nc * 8];
            float y = 0.f;
            #pragma unroll
            for (int j = 0; j < 8; j++) {
                float Bn = bf2f((ushort_t)Bv[j]);
                float Cn = bf2f((ushort_t)Cv[j]);
                s[j] = fmaf(s[j], dA, a * Bn);
                y = fmaf(s[j], Cn, y);
            }
            y += __shfl_xor(y, 1, 64);
            y += __shfl_xor(y, 2, 64);
            y += __shfl_xor(y, 4, 64);
            y += __shfl_xor(y, 8, 64);
            if (nc == 0) ysh[tt][pl] = fmaf(Dh, xp, y);
        }
        __syncthreads();
        #pragma unroll
        for (int i = 0; i < 2; i++) {
            int idx = tid + i * 256;
            int r = idx >> 4, p = idx & 15;
            yv[(base + t0 + r) * DINNER + pcol + p] = f2bf(ysh[r][p]);
        }
        __syncthreads();
    }
}

// ---------------- gate (y * silu(z)) + RMSNorm -> bf16 ----------------
__global__ __launch_bounds__(256) void gate_rms(const ushort_t* __restrict__ yv,
        const float* __restrict__ zxb, const float* __restrict__ rms_w,
        ushort_t* __restrict__ ynorm) {
    int r = blockIdx.x, t = threadIdx.x;
    const ushort_t* yr = yv + (size_t)r * DINNER;
    const float* zr = zxb + (size_t)r * NPAD;
    ushort8 y8 = *(const ushort8*)&yr[t * 8];
    float4 z0 = *(const float4*)&zr[t * 8];
    float4 z1 = *(const float4*)&zr[t * 8 + 4];
    float g[8];
    g[0] = bf2f((ushort_t)y8[0]) * siluf(z0.x);
    g[1] = bf2f((ushort_t)y8[1]) * siluf(z0.y);
    g[2] = bf2f((ushort_t)y8[2]) * siluf(z0.z);
    g[3] = bf2f((ushort_t)y8[3]) * siluf(z0.w);
    g[4] = bf2f((ushort_t)y8[4]) * siluf(z1.x);
    g[5] = bf2f((ushort_t)y8[5]) * siluf(z1.y);
    g[6] = bf2f((ushort_t)y8[6]) * siluf(z1.z);
    g[7] = bf2f((ushort_t)y8[7]) * siluf(z1.w);
    float sq = 0.f;
    #pragma unroll
    for (int j = 0; j < 8; j++) sq += g[j] * g[j];
    __shared__ float red[4];
    #pragma unroll
    for (int m = 32; m >= 1; m >>= 1) sq += __shfl_xor(sq, m, 64);
    int wv = t >> 6;
    if ((t & 63) == 0) red[wv] = sq;
    __syncthreads();
    sq = red[0] + red[1] + red[2] + red[3];
    float scale = rsqrtf(sq * (1.f / DINNER) + EPSF);
    float4 w0 = *(const float4*)&rms_w[t * 8];
    float4 w1 = *(const float4*)&rms_w[t * 8 + 4];
    ushort8 o;
    o[0] = f2bf(g[0] * scale * w0.x);
    o[1] = f2bf(g[1] * scale * w0.y);
    o[2] = f2bf(g[2] * scale * w0.z);
    o[3] = f2bf(g[3] * scale * w0.w);
    o[4] = f2bf(g[4] * scale * w1.x);
    o[5] = f2bf(g[5] * scale * w1.y);
    o[6] = f2bf(g[6] * scale * w1.z);
    o[7] = f2bf(g[7] * scale * w1.w);
    *(ushort8*)&ynorm[(size_t)r * DINNER + t * 8] = o;
}

extern "C" void kernel_launch(void* const* d_in, const int* in_sizes, int n_in,
                              void* d_out, int out_size, void* d_ws, size_t ws_size,
                              hipStream_t stream) {
    (void)in_sizes; (void)n_in; (void)out_size; (void)ws_size;
    const float* x       = (const float*)d_in[0];
    const float* ln_w    = (const float*)d_in[1];
    const float* ln_b    = (const float*)d_in[2];
    const float* W_in    = (const float*)d_in[3];
    const float* conv_w  = (const float*)d_in[4];
    const float* conv_b  = (const float*)d_in[5];
    const float* dt_bias = (const float*)d_in[6];
    const float* A_log   = (const float*)d_in[7];
    const float* Dvec    = (const float*)d_in[8];
    const float* rms_w   = (const float*)d_in[9];
    const float* W_out   = (const float*)d_in[10];
    float* out = (float*)d_out;

    char* ws = (char*)d_ws;
    size_t off = 0;
    auto alloc = [&](size_t bytes) -> void* {
        void* p = ws + off;
        off += (bytes + 255) & ~(size_t)255;
        return p;
    };
    ushort_t* xn    = (ushort_t*)alloc((size_t)BL * DMODEL * 2);
    ushort_t* WinT  = (ushort_t*)alloc((size_t)NPAD * DMODEL * 2);
    float*    zxb   = (float*)   alloc((size_t)BL * NPAD * 4);
    ushort_t* xcv   = (ushort_t*)alloc((size_t)BL * DINNER * 2);
    ushort_t* Bcg   = (ushort_t*)alloc((size_t)BL * DSTATE * 2);
    ushort_t* Ccg   = (ushort_t*)alloc((size_t)BL * DSTATE * 2);
    float*    dtv   = (float*)   alloc((size_t)BL * NHEADS * 4);
    float*    dAv   = (float*)   alloc((size_t)BL * NHEADS * 4);
    ushort_t* yv    = (ushort_t*)alloc((size_t)BL * DINNER * 2);
    ushort_t* ynorm = (ushort_t*)alloc((size_t)BL * DINNER * 2);
    ushort_t* WoutT = (ushort_t*)alloc((size_t)DMODEL * DINNER * 2);

    ln_kernel<<<BL, 256, 0, stream>>>(x, ln_w, ln_b, xn);
    transpose_cast<<<dim3(NPAD / 32, DMODEL / 32), 256, 0, stream>>>(W_in, WinT, DMODEL, DPROJ);
    transpose_cast<<<dim3(DMODEL / 32, DINNER / 32), 256, 0, stream>>>(W_out, WoutT, DINNER, DMODEL);
    gemm_bt<<<dim3(NPAD / 128, BL / 128), 256, 0, stream>>>(xn, WinT, zxb, nullptr, DMODEL, NPAD);
    conv_kernel<<<BL, 256, 0, stream>>>(zxb, conv_w, conv_b, dt_bias, A_log, xcv, Bcg, Ccg, dtv, dAv);
    scan_kernel<<<dim3(8, NHEADS, BATCH), 256, 0, stream>>>(xcv, Bcg, Ccg, dtv, dAv, Dvec, yv);
    gate_rms<<<BL, 256, 0, stream>>>(yv, zxb, rms_w, ynorm);
    gemm_bt<<<dim3(DMODEL / 128, BL / 128), 256, 0, stream>>>(ynorm, WoutT, out, x, DINNER, DMODEL);
}

// Round 2
// 410.508 us; speedup vs baseline: 1.9291x; 1.9291x over previous
//
#include <hip/hip_runtime.h>

typedef unsigned short ushort_t;
typedef __attribute__((ext_vector_type(8))) unsigned short ushort8;
typedef __attribute__((ext_vector_type(4))) unsigned short ushortv4;
typedef __attribute__((ext_vector_type(8))) __bf16 bf16x8;
typedef __attribute__((ext_vector_type(4))) float f32x4;

#define BATCH   2
#define SEQLEN  2048
#define BL      4096
#define DMODEL  1024
#define DINNER  2048
#define DSTATE  128
#define NHEADS  16
#define DXBC    2304
#define DPROJ   4368
#define NPAD    4480
#define EPSF    1e-5f

__device__ __forceinline__ float bf2f(ushort_t h) {
    unsigned int u = ((unsigned int)h) << 16;
    float f; __builtin_memcpy(&f, &u, 4); return f;
}
__device__ __forceinline__ ushort_t f2bf(float f) {
    unsigned int u; __builtin_memcpy(&u, &f, 4);
    unsigned int r = u + 0x7fffu + ((u >> 16) & 1u);
    return (ushort_t)(r >> 16);
}
__device__ __forceinline__ float siluf(float x) { return x / (1.f + expf(-x)); }
__device__ __forceinline__ float softplusf(float x) { return (x > 20.f) ? x : log1pf(expf(x)); }

// ---------------- LayerNorm + cast to bf16 ----------------
__global__ __launch_bounds__(256) void ln_kernel(const float* __restrict__ x,
        const float* __restrict__ w, const float* __restrict__ b, ushort_t* __restrict__ xn) {
    int r = blockIdx.x, t = threadIdx.x;
    const float* xr = x + (size_t)r * DMODEL;
    float4 v = *(const float4*)&xr[t * 4];
    float s  = v.x + v.y + v.z + v.w;
    float sq = v.x*v.x + v.y*v.y + v.z*v.z + v.w*v.w;
    __shared__ float red[8];
    #pragma unroll
    for (int m = 32; m >= 1; m >>= 1) { s += __shfl_xor(s, m, 64); sq += __shfl_xor(sq, m, 64); }
    int wv = t >> 6;
    if ((t & 63) == 0) { red[wv] = s; red[4 + wv] = sq; }
    __syncthreads();
    s  = red[0] + red[1] + red[2] + red[3];
    sq = red[4] + red[5] + red[6] + red[7];
    float mu  = s * (1.f / DMODEL);
    float var = sq * (1.f / DMODEL) - mu * mu;
    float inv = rsqrtf(var + EPSF);
    float4 wv4 = *(const float4*)&w[t * 4];
    float4 bv4 = *(const float4*)&b[t * 4];
    ushortv4 o;
    o[0] = f2bf((v.x - mu) * inv * wv4.x + bv4.x);
    o[1] = f2bf((v.y - mu) * inv * wv4.y + bv4.y);
    o[2] = f2bf((v.z - mu) * inv * wv4.z + bv4.z);
    o[3] = f2bf((v.w - mu) * inv * wv4.w + bv4.w);
    *(ushortv4*)&xn[(size_t)r * DMODEL + t * 4] = o;
}

// ---------------- transpose + cast f32[K][N] -> bf16[Npad][K] ----------------
__global__ __launch_bounds__(256) void transpose_cast(const float* __restrict__ W,
        ushort_t* __restrict__ WT, int K, int N) {
    __shared__ float tile[32][33];
    int n0 = blockIdx.x * 32, k0 = blockIdx.y * 32;
    int tx = threadIdx.x & 31, ty = threadIdx.x >> 5;
    #pragma unroll
    for (int i = 0; i < 32; i += 8) {
        int n = n0 + tx;
        tile[ty + i][tx] = (n < N) ? W[(size_t)(k0 + ty + i) * N + n] : 0.f;
    }
    __syncthreads();
    #pragma unroll
    for (int i = 0; i < 32; i += 8) {
        WT[(size_t)(n0 + ty + i) * K + k0 + tx] = f2bf(tile[tx][ty + i]);
    }
}

// ---------------- GEMM: C[M][ldc] = A[M][K](bf16) @ BT[N][K](bf16)^T (+resid) ----------------
__global__ __launch_bounds__(256) void gemm_bt(const ushort_t* __restrict__ A,
        const ushort_t* __restrict__ BT, float* __restrict__ C,
        const float* __restrict__ resid, int K, int ldc) {
    const int tid = threadIdx.x;
    const int m0 = blockIdx.y * 128, n0 = blockIdx.x * 128;
    __shared__ ushort_t As[128 * 32];
    __shared__ ushort_t Bs[128 * 32];
    const int row = tid >> 1;
    const int kh  = (tid & 1) * 16;
    const ushort_t* Ag = A  + (size_t)(m0 + row) * K + kh;
    const ushort_t* Bg = BT + (size_t)(n0 + row) * K + kh;
    ushort8 ra0 = *(const ushort8*)(Ag),     ra1 = *(const ushort8*)(Ag + 8);
    ushort8 rb0 = *(const ushort8*)(Bg),     rb1 = *(const ushort8*)(Bg + 8);
    const int lane = tid & 63, wave = tid >> 6;
    const int wm = (wave >> 1) * 64, wn = (wave & 1) * 64;
    const int fr = lane & 15, ko = (lane >> 4) * 8;
    f32x4 acc[4][4];
    #pragma unroll
    for (int i = 0; i < 4; i++)
        #pragma unroll
        for (int j = 0; j < 4; j++) acc[i][j] = (f32x4){0.f, 0.f, 0.f, 0.f};
    for (int k0 = 0; k0 < K; k0 += 32) {
        __syncthreads();
        *(ushort8*)&As[row * 32 + kh]     = ra0;
        *(ushort8*)&As[row * 32 + kh + 8] = ra1;
        *(ushort8*)&Bs[row * 32 + kh]     = rb0;
        *(ushort8*)&Bs[row * 32 + kh + 8] = rb1;
        __syncthreads();
        if (k0 + 32 < K) {
            ra0 = *(const ushort8*)(Ag + k0 + 32); ra1 = *(const ushort8*)(Ag + k0 + 40);
            rb0 = *(const ushort8*)(Bg + k0 + 32); rb1 = *(const ushort8*)(Bg + k0 + 40);
        }
        bf16x8 af[4], bfr[4];
        #pragma unroll
        for (int i = 0; i < 4; i++) af[i]  = *(const bf16x8*)&As[(wm + i * 16 + fr) * 32 + ko];
        #pragma unroll
        for (int j = 0; j < 4; j++) bfr[j] = *(const bf16x8*)&Bs[(wn + j * 16 + fr) * 32 + ko];
        #pragma unroll
        for (int i = 0; i < 4; i++)
            #pragma unroll
            for (int j = 0; j < 4; j++)
                acc[i][j] = __builtin_amdgcn_mfma_f32_16x16x32_bf16(af[i], bfr[j], acc[i][j], 0, 0, 0);
    }
    const int r0 = (lane >> 4) * 4;
    #pragma unroll
    for (int i = 0; i < 4; i++)
        #pragma unroll
        for (int j = 0; j < 4; j++)
            #pragma unroll
            for (int r = 0; r < 4; r++) {
                int m = m0 + wm + i * 16 + r0 + r;
                int n = n0 + wn + j * 16 + fr;
                float v = acc[i][j][r];
                if (resid) v += resid[(size_t)m * ldc + n];
                C[(size_t)m * ldc + n] = v;
            }
}

// ---------------- conv4 + SiLU + split + dt/dA ----------------
__global__ __launch_bounds__(256) void conv_kernel(const float* __restrict__ zxb,
        const float* __restrict__ conv_w, const float* __restrict__ conv_b,
        const float* __restrict__ dt_bias, const float* __restrict__ A_log,
        ushort_t* __restrict__ xcv, ushort_t* __restrict__ Bcg, ushort_t* __restrict__ Ccg,
        float* __restrict__ dtv, float* __restrict__ dAv) {
    int bid = blockIdx.x;
    int l = bid & (SEQLEN - 1);
    int tid = threadIdx.x;
    const float* rowp = zxb + (size_t)bid * NPAD;
    #pragma unroll 1
    for (int i = 0; i < 9; i++) {
        int c = tid + i * 256;
        float acc = conv_b[c];
        #pragma unroll
        for (int k = 0; k < 4; k++) {
            int ll = l - 3 + k;
            if (ll >= 0) acc += rowp[(ptrdiff_t)(k - 3) * NPAD + DINNER + c] * conv_w[c * 4 + k];
        }
        float v = siluf(acc);
        if (c < DINNER)                xcv[(size_t)bid * DINNER + c] = f2bf(v);
        else if (c < DINNER + DSTATE)  Bcg[(size_t)bid * DSTATE + (c - DINNER)] = f2bf(v);
        else                           Ccg[(size_t)bid * DSTATE + (c - DINNER - DSTATE)] = f2bf(v);
    }
    if (tid < NHEADS) {
        float raw = rowp[DINNER + DXBC + tid] + dt_bias[tid];
        float dt = softplusf(raw);
        float A = -expf(A_log[tid]);
        dtv[(size_t)bid * NHEADS + tid] = dt;
        dAv[(size_t)bid * NHEADS + tid] = expf(dt * A);
    }
}

// ---------------- SSM scan v2: deferred reduction, no per-timestep shuffles ----------------
// grid (psl 16, h 16, b 2) = 512 blocks, 256 threads.
// Block: 8 p-rows (pcol = h*128 + psl*8), all 128 n.
// Thread: pl = tid>>5 (one p), nc = tid&31 (4 n's: nc*4..nc*4+3). State s[4] in regs.
__global__ __launch_bounds__(256) void scan_kernel(const ushort_t* __restrict__ xcv,
        const ushort_t* __restrict__ Bcg, const ushort_t* __restrict__ Ccg,
        const float* __restrict__ dtv, const float* __restrict__ dAv,
        const float* __restrict__ Dvec, ushort_t* __restrict__ yv) {
    const int psl = blockIdx.x, h = blockIdx.y, b = blockIdx.z;
    const int tid = threadIdx.x;
    const int pl = tid >> 5, nc = tid & 31;
    __shared__ ushort_t Bsh[32][128];        // 8 KB
    __shared__ ushort_t Csh[32][128];        // 8 KB
    __shared__ float xsf[32][8];             // 1 KB
    __shared__ float dts[32];
    __shared__ float dAs[32];
    __shared__ float psh[32 * 8 * 33];       // partials [tt][pl][nc], stride-33 pad (33.8 KB)
    float s0 = 0.f, s1 = 0.f, s2 = 0.f, s3 = 0.f;
    const float Dh = Dvec[h];
    const size_t base = (size_t)b * SEQLEN;
    const int pcol = h * 128 + psl * 8;

    // staging maps
    const int r0s = tid >> 4, c8s = (tid & 15) * 8;       // B/C unit 0
    const int r1s = (tid + 256) >> 4;                     // B/C unit 1 (same c8s)
    const int xr = tid >> 3, xp = tid & 7;                // x map

    ushort8 pb0, pb1, pc0, pc1; ushort_t pxv; float pdt = 0.f, pda = 0.f;
    // prefetch chunk 0
    pb0 = *(const ushort8*)&Bcg[(base + r0s) * DSTATE + c8s];
    pb1 = *(const ushort8*)&Bcg[(base + r1s) * DSTATE + c8s];
    pc0 = *(const ushort8*)&Ccg[(base + r0s) * DSTATE + c8s];
    pc1 = *(const ushort8*)&Ccg[(base + r1s) * DSTATE + c8s];
    pxv = xcv[(base + xr) * DINNER + pcol + xp];
    if (tid < 32) {
        pdt = dtv[(base + tid) * NHEADS + h];
        pda = dAv[(base + tid) * NHEADS + h];
    }

    for (int t0 = 0; t0 < SEQLEN; t0 += 32) {
        *(ushort8*)&Bsh[r0s][c8s] = pb0;
        *(ushort8*)&Bsh[r1s][c8s] = pb1;
        *(ushort8*)&Csh[r0s][c8s] = pc0;
        *(ushort8*)&Csh[r1s][c8s] = pc1;
        xsf[xr][xp] = bf2f(pxv);
        if (tid < 32) { dts[tid] = pdt; dAs[tid] = pda; }
        __syncthreads();
        if (t0 + 32 < SEQLEN) {
            const size_t nb = base + t0 + 32;
            pb0 = *(const ushort8*)&Bcg[(nb + r0s) * DSTATE + c8s];
            pb1 = *(const ushort8*)&Bcg[(nb + r1s) * DSTATE + c8s];
            pc0 = *(const ushort8*)&Ccg[(nb + r0s) * DSTATE + c8s];
            pc1 = *(const ushort8*)&Ccg[(nb + r1s) * DSTATE + c8s];
            pxv = xcv[(nb + xr) * DINNER + pcol + xp];
            if (tid < 32) {
                pdt = dtv[(nb + tid) * NHEADS + h];
                pda = dAv[(nb + tid) * NHEADS + h];
            }
        }
        float* prow = &psh[pl * 33 + nc];
        #pragma unroll 4
        for (int tt = 0; tt < 32; tt++) {
            float dA = dAs[tt];
            float a  = dts[tt] * xsf[tt][pl];
            ushortv4 Bv = *(const ushortv4*)&Bsh[tt][nc * 4];
            ushortv4 Cv = *(const ushortv4*)&Csh[tt][nc * 4];
            float b0 = bf2f(Bv[0]), b1 = bf2f(Bv[1]), b2 = bf2f(Bv[2]), b3 = bf2f(Bv[3]);
            float c0 = bf2f(Cv[0]), c1 = bf2f(Cv[1]), c2 = bf2f(Cv[2]), c3 = bf2f(Cv[3]);
            s0 = fmaf(s0, dA, a * b0);
            s1 = fmaf(s1, dA, a * b1);
            s2 = fmaf(s2, dA, a * b2);
            s3 = fmaf(s3, dA, a * b3);
            float ya = fmaf(s1, c1, s0 * c0);
            float yb = fmaf(s3, c3, s2 * c2);
            prow[tt * 264] = ya + yb;         // ds_write_b32, fire-and-forget
        }
        __syncthreads();
        {   // reduce: one (tt,pl) row per thread, conflict-free stride-33 scalar reads
            const float* rr = &psh[tid * 33];
            float a0 = 0.f, a1 = 0.f, a2 = 0.f, a3 = 0.f;
            #pragma unroll
            for (int k = 0; k < 32; k += 4) {
                a0 += rr[k]; a1 += rr[k + 1]; a2 += rr[k + 2]; a3 += rr[k + 3];
            }
            int tt = tid >> 3, pp = tid & 7;
            float yo = (a0 + a1) + (a2 + a3) + Dh * xsf[tt][pp];
            yv[(base + t0 + tt) * DINNER + pcol + pp] = f2bf(yo);
        }
        __syncthreads();
    }
}

// ---------------- gate (y * silu(z)) + RMSNorm -> bf16 ----------------
__global__ __launch_bounds__(256) void gate_rms(const ushort_t* __restrict__ yv,
        const float* __restrict__ zxb, const float* __restrict__ rms_w,
        ushort_t* __restrict__ ynorm) {
    int r = blockIdx.x, t = threadIdx.x;
    const ushort_t* yr = yv + (size_t)r * DINNER;
    const float* zr = zxb + (size_t)r * NPAD;
    ushort8 y8 = *(const ushort8*)&yr[t * 8];
    float4 z0 = *(const float4*)&zr[t * 8];
    float4 z1 = *(const float4*)&zr[t * 8 + 4];
    float g[8];
    g[0] = bf2f((ushort_t)y8[0]) * siluf(z0.x);
    g[1] = bf2f((ushort_t)y8[1]) * siluf(z0.y);
    g[2] = bf2f((ushort_t)y8[2]) * siluf(z0.z);
    g[3] = bf2f((ushort_t)y8[3]) * siluf(z0.w);
    g[4] = bf2f((ushort_t)y8[4]) * siluf(z1.x);
    g[5] = bf2f((ushort_t)y8[5]) * siluf(z1.y);
    g[6] = bf2f((ushort_t)y8[6]) * siluf(z1.z);
    g[7] = bf2f((ushort_t)y8[7]) * siluf(z1.w);
    float sq = 0.f;
    #pragma unroll
    for (int j = 0; j < 8; j++) sq += g[j] * g[j];
    __shared__ float red[4];
    #pragma unroll
    for (int m = 32; m >= 1; m >>= 1) sq += __shfl_xor(sq, m, 64);
    int wv = t >> 6;
    if ((t & 63) == 0) red[wv] = sq;
    __syncthreads();
    sq = red[0] + red[1] + red[2] + red[3];
    float scale = rsqrtf(sq * (1.f / DINNER) + EPSF);
    float4 w0 = *(const float4*)&rms_w[t * 8];
    float4 w1 = *(const float4*)&rms_w[t * 8 + 4];
    ushort8 o;
    o[0] = f2bf(g[0] * scale * w0.x);
    o[1] = f2bf(g[1] * scale * w0.y);
    o[2] = f2bf(g[2] * scale * w0.z);
    o[3] = f2bf(g[3] * scale * w0.w);
    o[4] = f2bf(g[4] * scale * w1.x);
    o[5] = f2bf(g[5] * scale * w1.y);
    o[6] = f2bf(g[6] * scale * w1.z);
    o[7] = f2bf(g[7] * scale * w1.w);
    *(ushort8*)&ynorm[(size_t)r * DINNER + t * 8] = o;
}

extern "C" void kernel_launch(void* const* d_in, const int* in_sizes, int n_in,
                              void* d_out, int out_size, void* d_ws, size_t ws_size,
                              hipStream_t stream) {
    (void)in_sizes; (void)n_in; (void)out_size; (void)ws_size;
    const float* x       = (const float*)d_in[0];
    const float* ln_w    = (const float*)d_in[1];
    const float* ln_b    = (const float*)d_in[2];
    const float* W_in    = (const float*)d_in[3];
    const float* conv_w  = (const float*)d_in[4];
    const float* conv_b  = (const float*)d_in[5];
    const float* dt_bias = (const float*)d_in[6];
    const float* A_log   = (const float*)d_in[7];
    const float* Dvec    = (const float*)d_in[8];
    const float* rms_w   = (const float*)d_in[9];
    const float* W_out   = (const float*)d_in[10];
    float* out = (float*)d_out;

    char* ws = (char*)d_ws;
    size_t off = 0;
    auto alloc = [&](size_t bytes) -> void* {
        void* p = ws + off;
        off += (bytes + 255) & ~(size_t)255;
        return p;
    };
    ushort_t* xn    = (ushort_t*)alloc((size_t)BL * DMODEL * 2);
    ushort_t* WinT  = (ushort_t*)alloc((size_t)NPAD * DMODEL * 2);
    float*    zxb   = (float*)   alloc((size_t)BL * NPAD * 4);
    ushort_t* xcv   = (ushort_t*)alloc((size_t)BL * DINNER * 2);
    ushort_t* Bcg   = (ushort_t*)alloc((size_t)BL * DSTATE * 2);
    ushort_t* Ccg   = (ushort_t*)alloc((size_t)BL * DSTATE * 2);
    float*    dtv   = (float*)   alloc((size_t)BL * NHEADS * 4);
    float*    dAv   = (float*)   alloc((size_t)BL * NHEADS * 4);
    ushort_t* yv    = (ushort_t*)alloc((size_t)BL * DINNER * 2);
    ushort_t* ynorm = (ushort_t*)alloc((size_t)BL * DINNER * 2);
    ushort_t* WoutT = (ushort_t*)alloc((size_t)DMODEL * DINNER * 2);

    ln_kernel<<<BL, 256, 0, stream>>>(x, ln_w, ln_b, xn);
    transpose_cast<<<dim3(NPAD / 32, DMODEL / 32), 256, 0, stream>>>(W_in, WinT, DMODEL, DPROJ);
    transpose_cast<<<dim3(DMODEL / 32, DINNER / 32), 256, 0, stream>>>(W_out, WoutT, DINNER, DMODEL);
    gemm_bt<<<dim3(NPAD / 128, BL / 128), 256, 0, stream>>>(xn, WinT, zxb, nullptr, DMODEL, NPAD);
    conv_kernel<<<BL, 256, 0, stream>>>(zxb, conv_w, conv_b, dt_bias, A_log, xcv, Bcg, Ccg, dtv, dAv);
    scan_kernel<<<dim3(16, NHEADS, BATCH), 256, 0, stream>>>(xcv, Bcg, Ccg, dtv, dAv, Dvec, yv);
    gate_rms<<<BL, 256, 0, stream>>>(yv, zxb, rms_w, ynorm);
    gemm_bt<<<dim3(DMODEL / 128, BL / 128), 256, 0, stream>>>(ynorm, WoutT, out, x, DINNER, DMODEL);
}

// Round 3
// 245.375 us; speedup vs baseline: 3.2273x; 1.6730x over previous
//
#include <hip/hip_runtime.h>

typedef unsigned short ushort_t;
typedef __attribute__((ext_vector_type(8))) unsigned short ushort8;
typedef __attribute__((ext_vector_type(4))) unsigned short ushortv4;
typedef __attribute__((ext_vector_type(8))) __bf16 bf16x8;
typedef __attribute__((ext_vector_type(4))) float f32x4;

#define BATCH   2
#define SEQLEN  2048
#define BL      4096
#define DMODEL  1024
#define DINNER  2048
#define DSTATE  128
#define NHEADS  16
#define DXBC    2304
#define DPROJ   4368
#define NPAD    4480
#define EPSF    1e-5f
#define QCH     128
#define NCH     16          // SEQLEN / QCH
#define BH      32          // BATCH * NHEADS

// swizzled byte offset within a 256-byte LDS row (bf16, 128 cols)
#define SWZ(row, colbyte) ((colbyte) ^ (((row) & 7) << 4))

__device__ __forceinline__ float bf2f(ushort_t h) {
    unsigned int u = ((unsigned int)h) << 16;
    float f; __builtin_memcpy(&f, &u, 4); return f;
}
__device__ __forceinline__ ushort_t f2bf(float f) {
    unsigned int u; __builtin_memcpy(&u, &f, 4);
    unsigned int r = u + 0x7fffu + ((u >> 16) & 1u);
    return (ushort_t)(r >> 16);
}
__device__ __forceinline__ float siluf(float x) { return x / (1.f + expf(-x)); }
__device__ __forceinline__ float softplusf(float x) { return (x > 20.f) ? x : log1pf(expf(x)); }

// ---------------- LayerNorm + cast to bf16 ----------------
__global__ __launch_bounds__(256) void ln_kernel(const float* __restrict__ x,
        const float* __restrict__ w, const float* __restrict__ b, ushort_t* __restrict__ xn) {
    int r = blockIdx.x, t = threadIdx.x;
    const float* xr = x + (size_t)r * DMODEL;
    float4 v = *(const float4*)&xr[t * 4];
    float s  = v.x + v.y + v.z + v.w;
    float sq = v.x*v.x + v.y*v.y + v.z*v.z + v.w*v.w;
    __shared__ float red[8];
    #pragma unroll
    for (int m = 32; m >= 1; m >>= 1) { s += __shfl_xor(s, m, 64); sq += __shfl_xor(sq, m, 64); }
    int wv = t >> 6;
    if ((t & 63) == 0) { red[wv] = s; red[4 + wv] = sq; }
    __syncthreads();
    s  = red[0] + red[1] + red[2] + red[3];
    sq = red[4] + red[5] + red[6] + red[7];
    float mu  = s * (1.f / DMODEL);
    float var = sq * (1.f / DMODEL) - mu * mu;
    float inv = rsqrtf(var + EPSF);
    float4 wv4 = *(const float4*)&w[t * 4];
    float4 bv4 = *(const float4*)&b[t * 4];
    ushortv4 o;
    o[0] = f2bf((v.x - mu) * inv * wv4.x + bv4.x);
    o[1] = f2bf((v.y - mu) * inv * wv4.y + bv4.y);
    o[2] = f2bf((v.z - mu) * inv * wv4.z + bv4.z);
    o[3] = f2bf((v.w - mu) * inv * wv4.w + bv4.w);
    *(ushortv4*)&xn[(size_t)r * DMODEL + t * 4] = o;
}

// ---------------- transpose + cast f32[K][N] -> bf16[Npad][K] ----------------
__global__ __launch_bounds__(256) void transpose_cast(const float* __restrict__ W,
        ushort_t* __restrict__ WT, int K, int N) {
    __shared__ float tile[32][33];
    int n0 = blockIdx.x * 32, k0 = blockIdx.y * 32;
    int tx = threadIdx.x & 31, ty = threadIdx.x >> 5;
    #pragma unroll
    for (int i = 0; i < 32; i += 8) {
        int n = n0 + tx;
        tile[ty + i][tx] = (n < N) ? W[(size_t)(k0 + ty + i) * N + n] : 0.f;
    }
    __syncthreads();
    #pragma unroll
    for (int i = 0; i < 32; i += 8) {
        WT[(size_t)(n0 + ty + i) * K + k0 + tx] = f2bf(tile[tx][ty + i]);
    }
}

// ---------------- GEMM: C[M][ldc] = A[M][K](bf16) @ BT[N][K](bf16)^T (+resid) ----------------
__global__ __launch_bounds__(256) void gemm_bt(const ushort_t* __restrict__ A,
        const ushort_t* __restrict__ BT, float* __restrict__ C,
        const float* __restrict__ resid, int K, int ldc) {
    const int tid = threadIdx.x;
    const int m0 = blockIdx.y * 128, n0 = blockIdx.x * 128;
    __shared__ ushort_t As[128 * 32];
    __shared__ ushort_t Bs[128 * 32];
    const int row = tid >> 1;
    const int kh  = (tid & 1) * 16;
    const ushort_t* Ag = A  + (size_t)(m0 + row) * K + kh;
    const ushort_t* Bg = BT + (size_t)(n0 + row) * K + kh;
    ushort8 ra0 = *(const ushort8*)(Ag),     ra1 = *(const ushort8*)(Ag + 8);
    ushort8 rb0 = *(const ushort8*)(Bg),     rb1 = *(const ushort8*)(Bg + 8);
    const int lane = tid & 63, wave = tid >> 6;
    const int wm = (wave >> 1) * 64, wn = (wave & 1) * 64;
    const int fr = lane & 15, ko = (lane >> 4) * 8;
    f32x4 acc[4][4];
    #pragma unroll
    for (int i = 0; i < 4; i++)
        #pragma unroll
        for (int j = 0; j < 4; j++) acc[i][j] = (f32x4){0.f, 0.f, 0.f, 0.f};
    for (int k0 = 0; k0 < K; k0 += 32) {
        __syncthreads();
        *(ushort8*)&As[row * 32 + kh]     = ra0;
        *(ushort8*)&As[row * 32 + kh + 8] = ra1;
        *(ushort8*)&Bs[row * 32 + kh]     = rb0;
        *(ushort8*)&Bs[row * 32 + kh + 8] = rb1;
        __syncthreads();
        if (k0 + 32 < K) {
            ra0 = *(const ushort8*)(Ag + k0 + 32); ra1 = *(const ushort8*)(Ag + k0 + 40);
            rb0 = *(const ushort8*)(Bg + k0 + 32); rb1 = *(const ushort8*)(Bg + k0 + 40);
        }
        bf16x8 af[4], bfr[4];
        #pragma unroll
        for (int i = 0; i < 4; i++) af[i]  = *(const bf16x8*)&As[(wm + i * 16 + fr) * 32 + ko];
        #pragma unroll
        for (int j = 0; j < 4; j++) bfr[j] = *(const bf16x8*)&Bs[(wn + j * 16 + fr) * 32 + ko];
        #pragma unroll
        for (int i = 0; i < 4; i++)
            #pragma unroll
            for (int j = 0; j < 4; j++)
                acc[i][j] = __builtin_amdgcn_mfma_f32_16x16x32_bf16(af[i], bfr[j], acc[i][j], 0, 0, 0);
    }
    const int r0 = (lane >> 4) * 4;
    #pragma unroll
    for (int i = 0; i < 4; i++)
        #pragma unroll
        for (int j = 0; j < 4; j++)
            #pragma unroll
            for (int r = 0; r < 4; r++) {
                int m = m0 + wm + i * 16 + r0 + r;
                int n = n0 + wn + j * 16 + fr;
                float v = acc[i][j][r];
                if (resid) v += resid[(size_t)m * ldc + n];
                C[(size_t)m * ldc + n] = v;
            }
}

// ---------------- conv4 + SiLU + split + dt/dtA ----------------
__global__ __launch_bounds__(256) void conv_kernel(const float* __restrict__ zxb,
        const float* __restrict__ conv_w, const float* __restrict__ conv_b,
        const float* __restrict__ dt_bias, const float* __restrict__ A_log,
        ushort_t* __restrict__ xcv, ushort_t* __restrict__ Bcg, ushort_t* __restrict__ Ccg,
        float* __restrict__ dtv, float* __restrict__ dta) {
    int bid = blockIdx.x;
    int l = bid & (SEQLEN - 1);
    int tid = threadIdx.x;
    const float* rowp = zxb + (size_t)bid * NPAD;
    #pragma unroll 1
    for (int i = 0; i < 9; i++) {
        int c = tid + i * 256;
        float acc = conv_b[c];
        #pragma unroll
        for (int k = 0; k < 4; k++) {
            int ll = l - 3 + k;
            if (ll >= 0) acc += rowp[(ptrdiff_t)(k - 3) * NPAD + DINNER + c] * conv_w[c * 4 + k];
        }
        float v = siluf(acc);
        if (c < DINNER)                xcv[(size_t)bid * DINNER + c] = f2bf(v);
        else if (c < DINNER + DSTATE)  Bcg[(size_t)bid * DSTATE + (c - DINNER)] = f2bf(v);
        else                           Ccg[(size_t)bid * DSTATE + (c - DINNER - DSTATE)] = f2bf(v);
    }
    if (tid < NHEADS) {
        float raw = rowp[DINNER + DXBC + tid] + dt_bias[tid];
        float dt = softplusf(raw);
        float A = -expf(A_log[tid]);
        dtv[(size_t)bid * NHEADS + tid] = dt;
        dta[(size_t)bid * NHEADS + tid] = dt * A;
    }
}

// ---------------- per-chunk cumulative sums of dt*A ----------------
// grid (c, h, b), 128 threads. Outputs per (bh, c): ca[128] inclusive cumsum,
// expca = exp(ca), w = exp(ca_tot - ca)*dt, dtb = dt, dtot = exp(ca_tot).
__global__ __launch_bounds__(128) void cumsum_kernel(const float* __restrict__ dta,
        const float* __restrict__ dtv, float* __restrict__ cabuf, float* __restrict__ expca,
        float* __restrict__ wbuf, float* __restrict__ dtbuf, float* __restrict__ dtot) {
    const int c = blockIdx.x, h = blockIdx.y, b = blockIdx.z;
    const int bh = b * NHEADS + h;
    const int j = threadIdx.x;
    const size_t row = (size_t)b * SEQLEN + c * QCH + j;
    float v  = dta[row * NHEADS + h];
    float dt = dtv[row * NHEADS + h];
    float pv = v;
    #pragma unroll
    for (int off = 1; off < 64; off <<= 1) {
        float u = __shfl_up(pv, off, 64);
        if ((j & 63) >= off) pv += u;
    }
    __shared__ float wsum[2];
    if ((j & 63) == 63) wsum[j >> 6] = pv;
    __syncthreads();
    float tot = wsum[0] + wsum[1];
    if (j >= 64) pv += wsum[0];
    const size_t idx = ((size_t)bh * NCH + c) * QCH + j;
    cabuf[idx] = pv;
    expca[idx] = expf(pv);
    wbuf[idx]  = expf(tot - pv) * dt;
    dtbuf[idx] = dt;
    if (j == 0) dtot[bh * NCH + c] = expf(tot);
}

// ---------------- chunk end-state: states[bh][c][p][n] = sum_j w_j x[j][p] B[j][n] ----------------
__global__ __launch_bounds__(256) void chunkstate_kernel(const ushort_t* __restrict__ xcv,
        const ushort_t* __restrict__ Bcg, const float* __restrict__ wbuf,
        float* __restrict__ states) {
    const int c = blockIdx.x, h = blockIdx.y, b = blockIdx.z;
    const int bh = b * NHEADS + h;
    const int tid = threadIdx.x;
    __shared__ ushort_t Xt[128 * 128];     // [p][j] swizzled
    __shared__ ushort_t Bt[128 * 128];     // [n][j] swizzled
    __shared__ float wsh[QCH];
    if (tid < QCH) wsh[tid] = wbuf[((size_t)bh * NCH + c) * QCH + tid];
    __syncthreads();
    const size_t row0 = (size_t)b * SEQLEN + c * QCH;
    {
        const int f = tid & 127;
        const int jh = (tid >> 7) * 64;
        const ushort_t* xsrc = xcv + (row0 + jh) * DINNER + h * 128 + f;
        const ushort_t* bsrc = Bcg + (row0 + jh) * DSTATE + f;
        char* xrow = (char*)Xt + f * 256;
        char* brow = (char*)Bt + f * 256;
        #pragma unroll 2
        for (int e8 = 0; e8 < 8; e8++) {
            ushort8 tx, tb;
            #pragma unroll
            for (int e = 0; e < 8; e++) {
                int j = e8 * 8 + e;
                tx[e] = xsrc[(size_t)j * DINNER];
                tb[e] = f2bf(bf2f(bsrc[(size_t)j * DSTATE]) * wsh[jh + j]);
            }
            int cb = (jh + e8 * 8) * 2;
            *(ushort8*)(xrow + SWZ(f, cb)) = tx;
            *(ushort8*)(brow + SWZ(f, cb)) = tb;
        }
    }
    __syncthreads();
    const int lane = tid & 63, wave = tid >> 6;
    const int wp = (wave >> 1) * 64, wn = (wave & 1) * 64;
    const int fr = lane & 15, ko = (lane >> 4) * 8;
    f32x4 acc[4][4];
    #pragma unroll
    for (int i = 0; i < 4; i++)
        #pragma unroll
        for (int j = 0; j < 4; j++) acc[i][j] = (f32x4){0.f, 0.f, 0.f, 0.f};
    for (int k0 = 0; k0 < 128; k0 += 32) {
        bf16x8 af[4], bfr[4];
        #pragma unroll
        for (int i = 0; i < 4; i++) {
            int rp = wp + i * 16 + fr;
            af[i] = *(const bf16x8*)((const char*)Xt + rp * 256 + SWZ(rp, (k0 + ko) * 2));
        }
        #pragma unroll
        for (int j = 0; j < 4; j++) {
            int rn = wn + j * 16 + fr;
            bfr[j] = *(const bf16x8*)((const char*)Bt + rn * 256 + SWZ(rn, (k0 + ko) * 2));
        }
        #pragma unroll
        for (int i = 0; i < 4; i++)
            #pragma unroll
            for (int j = 0; j < 4; j++)
                acc[i][j] = __builtin_amdgcn_mfma_f32_16x16x32_bf16(af[i], bfr[j], acc[i][j], 0, 0, 0);
    }
    const int r0 = (lane >> 4) * 4;
    float* outp = states + ((size_t)bh * NCH + c) * 16384;
    #pragma unroll
    for (int i = 0; i < 4; i++)
        #pragma unroll
        for (int j = 0; j < 4; j++)
            #pragma unroll
            for (int r = 0; r < 4; r++)
                outp[(wp + i * 16 + r0 + r) * 128 + wn + j * 16 + fr] = acc[i][j][r];
}

// ---------------- inter-chunk state scan (in place): states[c] <- S_init(c) ----------------
__global__ __launch_bounds__(256) void statescan_kernel(float* __restrict__ states,
        const float* __restrict__ dtot) {
    const int pseg = blockIdx.x, bh = blockIdx.y;
    const int tid = threadIdx.x;
    const int p = pseg * 8 + (tid >> 5);
    const int n4 = (tid & 31) * 4;
    float* base = states + (size_t)bh * NCH * 16384 + p * 128 + n4;
    const float* dtp = dtot + bh * NCH;
    f32x4 run = (f32x4){0.f, 0.f, 0.f, 0.f};
    #pragma unroll 1
    for (int c = 0; c < NCH; c++) {
        f32x4* ptr = (f32x4*)(base + (size_t)c * 16384);
        f32x4 cs = *ptr;
        *ptr = run;
        float d = dtp[c];
        run = run * d + cs;
    }
}

// ---------------- chunk output: y = (mask(CB^T)) @ X + exp(ca) * (C @ S_init) ----------------
__global__ __launch_bounds__(256) void chunkout_kernel(const ushort_t* __restrict__ xcv,
        const ushort_t* __restrict__ Bcg, const ushort_t* __restrict__ Ccg,
        const float* __restrict__ states, const float* __restrict__ cabuf,
        const float* __restrict__ expca, const float* __restrict__ dtbuf,
        const float* __restrict__ Dvec, ushort_t* __restrict__ yv) {
    const int c = blockIdx.x, h = blockIdx.y, b = blockIdx.z;
    const int bh = b * NHEADS + h;
    const int tid = threadIdx.x;
    __shared__ ushort_t R1[128 * 128];   // B -> ST -> Xt
    __shared__ ushort_t R2[128 * 128];   // C
    __shared__ ushort_t R3[128 * 128];   // P [t][j]
    __shared__ float cash[QCH], dtsh[QCH], exsh[QCH];
    const size_t aidx = ((size_t)bh * NCH + c) * QCH;
    if (tid < QCH) {
        cash[tid] = cabuf[aidx + tid];
        dtsh[tid] = dtbuf[aidx + tid];
        exsh[tid] = expca[aidx + tid];
    }
    const size_t row0 = (size_t)b * SEQLEN + c * QCH;
    // stage B -> R1, C -> R2 (natural [t][n], swizzled rows)
    #pragma unroll
    for (int it = 0; it < 8; it++) {
        int g = tid + it * 256;
        int r = g >> 4, n8 = (g & 15) * 8;
        ushort8 vb = *(const ushort8*)&Bcg[(row0 + r) * DSTATE + n8];
        ushort8 vc = *(const ushort8*)&Ccg[(row0 + r) * DSTATE + n8];
        int cb = n8 * 2;
        *(ushort8*)((char*)R1 + r * 256 + SWZ(r, cb)) = vb;
        *(ushort8*)((char*)R2 + r * 256 + SWZ(r, cb)) = vc;
    }
    __syncthreads();
    const int lane = tid & 63, wave = tid >> 6;
    const int fr = lane & 15, ko = (lane >> 4) * 8, r0 = (lane >> 4) * 4;
    // GEMM1: Gt[j][t] = sum_n B[j][n] C[t][n]; quadrant: wj rows, wt cols
    const int wj = (wave >> 1) * 64, wt = (wave & 1) * 64;
    f32x4 g_[4][4];
    #pragma unroll
    for (int i = 0; i < 4; i++)
        #pragma unroll
        for (int t = 0; t < 4; t++) g_[i][t] = (f32x4){0.f, 0.f, 0.f, 0.f};
    if (!(wj == 64 && wt == 0)) {          // that quadrant is fully masked (j > t)
        for (int k0 = 0; k0 < 128; k0 += 32) {
            bf16x8 af[4], bfr[4];
            #pragma unroll
            for (int i = 0; i < 4; i++) {
                int rj = wj + i * 16 + fr;
                af[i] = *(const bf16x8*)((const char*)R1 + rj * 256 + SWZ(rj, (k0 + ko) * 2));
            }
            #pragma unroll
            for (int t = 0; t < 4; t++) {
                int rt = wt + t * 16 + fr;
                bfr[t] = *(const bf16x8*)((const char*)R2 + rt * 256 + SWZ(rt, (k0 + ko) * 2));
            }
            #pragma unroll
            for (int i = 0; i < 4; i++)
                #pragma unroll
                for (int t = 0; t < 4; t++)
                    g_[i][t] = __builtin_amdgcn_mfma_f32_16x16x32_bf16(af[i], bfr[t], g_[i][t], 0, 0, 0);
        }
    }
    // P[t][j] = mask(j<=t) * G * exp(ca[t]-ca[j]) * dt[j]  (+ D on diagonal), store bf16 to R3
    const float Dh = Dvec[h];
    #pragma unroll
    for (int i = 0; i < 4; i++) {
        #pragma unroll
        for (int t = 0; t < 4; t++) {
            int tt = wt + t * 16 + fr;
            int jj0 = wj + i * 16 + r0;
            ushortv4 pk;
            #pragma unroll
            for (int r = 0; r < 4; r++) {
                int jj = jj0 + r;
                float val = 0.f;
                if (jj <= tt) {
                    val = g_[i][t][r] * expf(cash[tt] - cash[jj]) * dtsh[jj];
                    if (jj == tt) val += Dh;
                }
                pk[r] = f2bf(val);
            }
            *(ushortv4*)((char*)R3 + tt * 256 + SWZ(tt, jj0 * 2)) = pk;
        }
    }
    __syncthreads();
    // stage S_init -> R1 as bf16 [p][n] swizzled
    {
        const float* sp = states + ((size_t)bh * NCH + c) * 16384;
        #pragma unroll
        for (int it = 0; it < 8; it++) {
            int g = tid + it * 256;
            int p = g >> 4, n8 = (g & 15) * 8;
            f32x4 a = *(const f32x4*)&sp[p * 128 + n8];
            f32x4 bq = *(const f32x4*)&sp[p * 128 + n8 + 4];
            ushort8 v;
            v[0] = f2bf(a[0]);  v[1] = f2bf(a[1]);  v[2] = f2bf(a[2]);  v[3] = f2bf(a[3]);
            v[4] = f2bf(bq[0]); v[5] = f2bf(bq[1]); v[6] = f2bf(bq[2]); v[7] = f2bf(bq[3]);
            *(ushort8*)((char*)R1 + p * 256 + SWZ(p, n8 * 2)) = v;
        }
    }
    __syncthreads();
    // GEMM3: Y[t][p] = sum_n C[t][n] ST[p][n]; quadrant: wty rows(t), wpy cols(p)
    const int wty = (wave >> 1) * 64, wpy = (wave & 1) * 64;
    f32x4 y_[4][4];
    #pragma unroll
    for (int i = 0; i < 4; i++)
        #pragma unroll
        for (int j = 0; j < 4; j++) y_[i][j] = (f32x4){0.f, 0.f, 0.f, 0.f};
    for (int k0 = 0; k0 < 128; k0 += 32) {
        bf16x8 af[4], bfr[4];
        #pragma unroll
        for (int i = 0; i < 4; i++) {
            int rt = wty + i * 16 + fr;
            af[i] = *(const bf16x8*)((const char*)R2 + rt * 256 + SWZ(rt, (k0 + ko) * 2));
        }
        #pragma unroll
        for (int j = 0; j < 4; j++) {
            int rp = wpy + j * 16 + fr;
            bfr[j] = *(const bf16x8*)((const char*)R1 + rp * 256 + SWZ(rp, (k0 + ko) * 2));
        }
        #pragma unroll
        for (int i = 0; i < 4; i++)
            #pragma unroll
            for (int j = 0; j < 4; j++)
                y_[i][j] = __builtin_amdgcn_mfma_f32_16x16x32_bf16(af[i], bfr[j], y_[i][j], 0, 0, 0);
    }
    // scale inter-chunk term by exp(ca[t])
    #pragma unroll
    for (int i = 0; i < 4; i++)
        #pragma unroll
        for (int r = 0; r < 4; r++) {
            float sc = exsh[wty + i * 16 + r0 + r];
            #pragma unroll
            for (int j = 0; j < 4; j++) y_[i][j][r] *= sc;
        }
    __syncthreads();
    // stage X^T -> R1: [p][j] swizzled
    {
        const int f = tid & 127;
        const int jh = (tid >> 7) * 64;
        const ushort_t* xsrc = xcv + (row0 + jh) * DINNER + h * 128 + f;
        char* xrow = (char*)R1 + f * 256;
        #pragma unroll 2
        for (int e8 = 0; e8 < 8; e8++) {
            ushort8 tx;
            #pragma unroll
            for (int e = 0; e < 8; e++) tx[e] = xsrc[(size_t)(e8 * 8 + e) * DINNER];
            int cb = (jh + e8 * 8) * 2;
            *(ushort8*)(xrow + SWZ(f, cb)) = tx;
        }
    }
    __syncthreads();
    // GEMM2: Y[t][p] += sum_j P[t][j] Xt[p][j]; j <= t so k0 < wty+64
    const int kmax = wty + 64;
    for (int k0 = 0; k0 < kmax; k0 += 32) {
        bf16x8 af[4], bfr[4];
        #pragma unroll
        for (int i = 0; i < 4; i++) {
            int rt = wty + i * 16 + fr;
            af[i] = *(const bf16x8*)((const char*)R3 + rt * 256 + SWZ(rt, (k0 + ko) * 2));
        }
        #pragma unroll
        for (int j = 0; j < 4; j++) {
            int rp = wpy + j * 16 + fr;
            bfr[j] = *(const bf16x8*)((const char*)R1 + rp * 256 + SWZ(rp, (k0 + ko) * 2));
        }
        #pragma unroll
        for (int i = 0; i < 4; i++)
            #pragma unroll
            for (int j = 0; j < 4; j++)
                y_[i][j] = __builtin_amdgcn_mfma_f32_16x16x32_bf16(af[i], bfr[j], y_[i][j], 0, 0, 0);
    }
    // epilogue: write y bf16
    #pragma unroll
    for (int i = 0; i < 4; i++)
        #pragma unroll
        for (int j = 0; j < 4; j++)
            #pragma unroll
            for (int r = 0; r < 4; r++) {
                int t = wty + i * 16 + r0 + r;
                int p = wpy + j * 16 + fr;
                yv[(row0 + t) * DINNER + h * 128 + p] = f2bf(y_[i][j][r]);
            }
}

// ---------------- gate (y * silu(z)) + RMSNorm -> bf16 ----------------
__global__ __launch_bounds__(256) void gate_rms(const ushort_t* __restrict__ yv,
        const float* __restrict__ zxb, const float* __restrict__ rms_w,
        ushort_t* __restrict__ ynorm) {
    int r = blockIdx.x, t = threadIdx.x;
    const ushort_t* yr = yv + (size_t)r * DINNER;
    const float* zr = zxb + (size_t)r * NPAD;
    ushort8 y8 = *(const ushort8*)&yr[t * 8];
    float4 z0 = *(const float4*)&zr[t * 8];
    float4 z1 = *(const float4*)&zr[t * 8 + 4];
    float g[8];
    g[0] = bf2f((ushort_t)y8[0]) * siluf(z0.x);
    g[1] = bf2f((ushort_t)y8[1]) * siluf(z0.y);
    g[2] = bf2f((ushort_t)y8[2]) * siluf(z0.z);
    g[3] = bf2f((ushort_t)y8[3]) * siluf(z0.w);
    g[4] = bf2f((ushort_t)y8[4]) * siluf(z1.x);
    g[5] = bf2f((ushort_t)y8[5]) * siluf(z1.y);
    g[6] = bf2f((ushort_t)y8[6]) * siluf(z1.z);
    g[7] = bf2f((ushort_t)y8[7]) * siluf(z1.w);
    float sq = 0.f;
    #pragma unroll
    for (int j = 0; j < 8; j++) sq += g[j] * g[j];
    __shared__ float red[4];
    #pragma unroll
    for (int m = 32; m >= 1; m >>= 1) sq += __shfl_xor(sq, m, 64);
    int wv = t >> 6;
    if ((t & 63) == 0) red[wv] = sq;
    __syncthreads();
    sq = red[0] + red[1] + red[2] + red[3];
    float scale = rsqrtf(sq * (1.f / DINNER) + EPSF);
    float4 w0 = *(const float4*)&rms_w[t * 8];
    float4 w1 = *(const float4*)&rms_w[t * 8 + 4];
    ushort8 o;
    o[0] = f2bf(g[0] * scale * w0.x);
    o[1] = f2bf(g[1] * scale * w0.y);
    o[2] = f2bf(g[2] * scale * w0.z);
    o[3] = f2bf(g[3] * scale * w0.w);
    o[4] = f2bf(g[4] * scale * w1.x);
    o[5] = f2bf(g[5] * scale * w1.y);
    o[6] = f2bf(g[6] * scale * w1.z);
    o[7] = f2bf(g[7] * scale * w1.w);
    *(ushort8*)&ynorm[(size_t)r * DINNER + t * 8] = o;
}

extern "C" void kernel_launch(void* const* d_in, const int* in_sizes, int n_in,
                              void* d_out, int out_size, void* d_ws, size_t ws_size,
                              hipStream_t stream) {
    (void)in_sizes; (void)n_in; (void)out_size; (void)ws_size;
    const float* x       = (const float*)d_in[0];
    const float* ln_w    = (const float*)d_in[1];
    const float* ln_b    = (const float*)d_in[2];
    const float* W_in    = (const float*)d_in[3];
    const float* conv_w  = (const float*)d_in[4];
    const float* conv_b  = (const float*)d_in[5];
    const float* dt_bias = (const float*)d_in[6];
    const float* A_log   = (const float*)d_in[7];
    const float* Dvec    = (const float*)d_in[8];
    const float* rms_w   = (const float*)d_in[9];
    const float* W_out   = (const float*)d_in[10];
    float* out = (float*)d_out;

    char* ws = (char*)d_ws;
    size_t off = 0;
    auto alloc = [&](size_t bytes) -> void* {
        void* p = ws + off;
        off += (bytes + 255) & ~(size_t)255;
        return p;
    };
    ushort_t* xn    = (ushort_t*)alloc((size_t)BL * DMODEL * 2);
    ushort_t* WinT  = (ushort_t*)alloc((size_t)NPAD * DMODEL * 2);
    float*    zxb   = (float*)   alloc((size_t)BL * NPAD * 4);
    ushort_t* xcv   = (ushort_t*)alloc((size_t)BL * DINNER * 2);
    ushort_t* Bcg   = (ushort_t*)alloc((size_t)BL * DSTATE * 2);
    ushort_t* Ccg   = (ushort_t*)alloc((size_t)BL * DSTATE * 2);
    float*    dtv   = (float*)   alloc((size_t)BL * NHEADS * 4);
    float*    dta   = (float*)   alloc((size_t)BL * NHEADS * 4);
    ushort_t* yv    = (ushort_t*)alloc((size_t)BL * DINNER * 2);
    ushort_t* ynorm = (ushort_t*)alloc((size_t)BL * DINNER * 2);
    ushort_t* WoutT = (ushort_t*)alloc((size_t)DMODEL * DINNER * 2);
    float*    cabuf = (float*)   alloc((size_t)BH * NCH * QCH * 4);
    float*    expcb = (float*)   alloc((size_t)BH * NCH * QCH * 4);
    float*    wbuf  = (float*)   alloc((size_t)BH * NCH * QCH * 4);
    float*    dtbuf = (float*)   alloc((size_t)BH * NCH * QCH * 4);
    float*    dtot  = (float*)   alloc((size_t)BH * NCH * 4);
    float*    states= (float*)   alloc((size_t)BH * NCH * 16384 * 4);

    ln_kernel<<<BL, 256, 0, stream>>>(x, ln_w, ln_b, xn);
    transpose_cast<<<dim3(NPAD / 32, DMODEL / 32), 256, 0, stream>>>(W_in, WinT, DMODEL, DPROJ);
    transpose_cast<<<dim3(DMODEL / 32, DINNER / 32), 256, 0, stream>>>(W_out, WoutT, DINNER, DMODEL);
    gemm_bt<<<dim3(NPAD / 128, BL / 128), 256, 0, stream>>>(xn, WinT, zxb, nullptr, DMODEL, NPAD);
    conv_kernel<<<BL, 256, 0, stream>>>(zxb, conv_w, conv_b, dt_bias, A_log, xcv, Bcg, Ccg, dtv, dta);
    cumsum_kernel<<<dim3(NCH, NHEADS, BATCH), 128, 0, stream>>>(dta, dtv, cabuf, expcb, wbuf, dtbuf, dtot);
    chunkstate_kernel<<<dim3(NCH, NHEADS, BATCH), 256, 0, stream>>>(xcv, Bcg, wbuf, states);
    statescan_kernel<<<dim3(16, BH), 256, 0, stream>>>(states, dtot);
    chunkout_kernel<<<dim3(NCH, NHEADS, BATCH), 256, 0, stream>>>(xcv, Bcg, Ccg, states, cabuf, expcb, dtbuf, Dvec, yv);
    gate_rms<<<BL, 256, 0, stream>>>(yv, zxb, rms_w, ynorm);
    gemm_bt<<<dim3(DMODEL / 128, BL / 128), 256, 0, stream>>>(ynorm, WoutT, out, x, DINNER, DMODEL);
}